// Round 1
// baseline (644.632 us; speedup 1.0000x reference)
//
#include <hip/hip_runtime.h>
#include <hip/hip_bf16.h>

// Potts energy:  U (scalar) and U_i (N,C)
//   B=1, N=8192, K=32, C=21.  J is (N,K,C,C) f32 = 462 MB -> HBM-bound stream.
//
// Strategy: one 256-thread block per node i. Stream the node's contiguous
// K*C*C = 14112-float J block with float4 loads (perfect coalescing, 16B/lane).
// For element e: k=e/441, c=(e%441)/21, c2=e%21. Only elements with
// c2 == S_j[i,k] contribute: acc[c] += J_e * mask_ij[i,k]  (LDS atomic,
// only K*C=672 matches per block). Epilogue: U_i = h*mask_i + acc,
// U += U_i[S_i] - 0.5*acc[S_i] via one global float atomic per block.

#define KK 32
#define CC 21
#define BLOCK_ELEMS (KK * CC * CC)      // 14112 floats per node
#define BLOCK_VEC4  (BLOCK_ELEMS / 4)   // 3528 float4 per node

__global__ __launch_bounds__(256) void potts_kernel(
    const int* __restrict__ S,
    const float* __restrict__ h,
    const float* __restrict__ J,
    const int* __restrict__ edge_idx,
    const float* __restrict__ mask_i,
    const float* __restrict__ mask_ij,
    float* __restrict__ out)            // out[0]=U, out[1..]=U_i (N*C)
{
    const int i   = blockIdx.x;
    const int tid = threadIdx.x;

    __shared__ int   s_j[KK];
    __shared__ float m_ij[KK];
    __shared__ float acc[CC];
    __shared__ float ui_s[CC];

    if (tid < KK) {
        int e = edge_idx[i * KK + tid];
        s_j[tid]  = S[e];
        m_ij[tid] = mask_ij[i * KK + tid];
    }
    if (tid < CC) acc[tid] = 0.0f;
    __syncthreads();

    const float4* __restrict__ Jb =
        (const float4*)(J + (size_t)i * BLOCK_ELEMS);

    for (int q = tid; q < BLOCK_VEC4; q += 256) {
        float4 v = Jb[q];
        const float* vf = (const float*)&v;
        int e0 = q * 4;
#pragma unroll
        for (int j = 0; j < 4; ++j) {
            int e  = e0 + j;
            int k  = e / (CC * CC);          // magic-mul division (e < 2^24)
            int c2 = e % CC;                 // 441 is a multiple of 21
            if (c2 == s_j[k]) {
                int c = (e - k * (CC * CC)) / CC;
                atomicAdd(&acc[c], vf[j] * m_ij[k]);
            }
        }
    }
    __syncthreads();

    if (tid < CC) {
        float ui = h[i * CC + tid] * mask_i[i] + acc[tid];
        out[1 + i * CC + tid] = ui;
        ui_s[tid] = ui;
    }
    __syncthreads();

    if (tid == 0) {
        int s = S[i];
        float u = ui_s[s] - 0.5f * acc[s];
        atomicAdd(out, u);   // device-scope by default on CDNA
    }
}

extern "C" void kernel_launch(void* const* d_in, const int* in_sizes, int n_in,
                              void* d_out, int out_size, void* d_ws, size_t ws_size,
                              hipStream_t stream) {
    const int*   S        = (const int*)d_in[0];
    const float* h        = (const float*)d_in[1];
    const float* J        = (const float*)d_in[2];
    const int*   edge_idx = (const int*)d_in[3];
    const float* mask_i   = (const float*)d_in[4];
    const float* mask_ij  = (const float*)d_in[5];
    float* out = (float*)d_out;

    const int N = in_sizes[0];   // 8192 nodes

    // Harness poisons d_out with 0xAA before timed launches; U is accumulated
    // with atomics so zero it first (memsetAsync is graph-capture safe).
    hipMemsetAsync(out, 0, sizeof(float), stream);

    potts_kernel<<<N, 256, 0, stream>>>(S, h, J, edge_idx, mask_i, mask_ij, out);
}

// Round 2
// 630.049 us; speedup vs baseline: 1.0231x; 1.0231x over previous
//
#include <hip/hip_runtime.h>
#include <hip/hip_bf16.h>

// Potts energy:  U (scalar) and U_i (N,C);  B=1, N=8192, K=32, C=21.
//
// Gather formulation: only J[i,k,c,S_j[k]] (K*C = 672 floats/node) are needed.
// Row stride is 84 B < 128 B line, so HBM still streams ~all of J (462 MB,
// ~73 us floor @6.3 TB/s) -- but vs. the full-stream+select version this has
// ~5x fewer load instructions, no div/mod per element, no divergent branch in
// the hot path, and 3 independent gather loads in flight per thread.
//
// One 256-thread block per node: stage S_j[k], mask_ij[k] in LDS, gather 672
// elements (idx = k*21+c), LDS-atomicAdd into acc[c] (672 adds/block,
// negligible). Epilogue: U_i = h*mask_i + acc; U += U_i[S_i] - 0.5*acc[S_i]
// via one global float atomic per block (out[0] zeroed with memsetAsync).

#define KK 32
#define CC 21
#define PAIRS (KK * CC)                 // 672 needed elements per node

__global__ __launch_bounds__(256) void potts_kernel(
    const int* __restrict__ S,
    const float* __restrict__ h,
    const float* __restrict__ J,
    const int* __restrict__ edge_idx,
    const float* __restrict__ mask_i,
    const float* __restrict__ mask_ij,
    float* __restrict__ out)            // out[0]=U, out[1..]=U_i (N*C)
{
    const int i   = blockIdx.x;
    const int tid = threadIdx.x;

    __shared__ int   s_j[KK];
    __shared__ float m_ij[KK];
    __shared__ float acc[CC];
    __shared__ float ui_s[CC];

    if (tid < KK) {
        int e = edge_idx[i * KK + tid];
        s_j[tid]  = S[e];
        m_ij[tid] = mask_ij[i * KK + tid];
    }
    if (tid < CC) acc[tid] = 0.0f;
    __syncthreads();

    const float* __restrict__ Jb = J + (size_t)i * (KK * CC * CC);

    // Gather phase: 3 independent loads per thread (672 = 2*256 + 160).
    float vals[3];
    int   cs[3];
#pragma unroll
    for (int j = 0; j < 3; ++j) {
        int idx = tid + j * 256;
        if (idx < PAIRS) {
            int k = idx / CC;            // magic-mul, compile-time const 21
            int c = idx - k * CC;
            cs[j]   = c;
            vals[j] = Jb[k * (CC * CC) + c * CC + s_j[k]] * m_ij[k];
        } else {
            cs[j]   = -1;
            vals[j] = 0.0f;
        }
    }
#pragma unroll
    for (int j = 0; j < 3; ++j) {
        if (cs[j] >= 0) atomicAdd(&acc[cs[j]], vals[j]);
    }
    __syncthreads();

    if (tid < CC) {
        float ui = h[i * CC + tid] * mask_i[i] + acc[tid];
        out[1 + i * CC + tid] = ui;
        ui_s[tid] = ui;
    }
    __syncthreads();

    if (tid == 0) {
        int s = S[i];
        float u = ui_s[s] - 0.5f * acc[s];
        atomicAdd(out, u);   // device-scope by default on CDNA
    }
}

extern "C" void kernel_launch(void* const* d_in, const int* in_sizes, int n_in,
                              void* d_out, int out_size, void* d_ws, size_t ws_size,
                              hipStream_t stream) {
    const int*   S        = (const int*)d_in[0];
    const float* h        = (const float*)d_in[1];
    const float* J        = (const float*)d_in[2];
    const int*   edge_idx = (const int*)d_in[3];
    const float* mask_i   = (const float*)d_in[4];
    const float* mask_ij  = (const float*)d_in[5];
    float* out = (float*)d_out;

    const int N = in_sizes[0];   // 8192 nodes

    // Harness poisons d_out with 0xAA; U is atomically accumulated -> zero it.
    hipMemsetAsync(out, 0, sizeof(float), stream);

    potts_kernel<<<N, 256, 0, stream>>>(S, h, J, edge_idx, mask_i, mask_ij, out);
}